// Round 1
// 1100.989 us; speedup vs baseline: 1.0139x; 1.0139x over previous
//
#include <hip/hip_runtime.h>
#include <hip/hip_bf16.h>
#include <hip/hip_fp16.h>

#define T_STEPS 512
#define BATCH   64
#define DIM     512            // INPUT_DIM == RNN_DIM
// Per-thread K-half: 128 half2 pairs, split:
#define REG_PAIRS 80           // q in [0,80): pinned in VGPRs
#define LDS_PAIRS 32           // q in [80,112): staged in LDS (packed 4-pair b128)
#define STR_PAIRS 16           // q in [112,128): streamed from L2 each step (2 chunks of 8)

typedef _Float16 half2_t __attribute__((ext_vector_type(2)));
typedef _Float16 half8_t __attribute__((ext_vector_type(8)));
typedef short    bf16x8 __attribute__((ext_vector_type(8)));
typedef float    f32x4  __attribute__((ext_vector_type(4)));

static __device__ __forceinline__ unsigned short f2bf(float f) {
    union { float f; unsigned u; } v; v.f = f;
    unsigned r = v.u + 0x7fffu + ((v.u >> 16) & 1u);   // RNE
    return (unsigned short)(r >> 16);
}

static __device__ __forceinline__ float fast_tanh(float x) {
    float e = __expf(2.0f * x);
    return 1.0f - 2.0f * __builtin_amdgcn_rcpf(e + 1.0f);
}

// ------------- K1: transpose 512x512 fp32 region -> bf16 (for Wx^T) -------------
__global__ __launch_bounds__(256) void tr_cvt_kernel(const float* __restrict__ src,
                                                     unsigned short* __restrict__ dst) {
    __shared__ float tile[32][33];
    const int bx = blockIdx.x * 32;
    const int by = blockIdx.y * 32;
    const int tx = threadIdx.x;       // 32
    const int ty = threadIdx.y;       // 8
    #pragma unroll
    for (int i = ty; i < 32; i += 8)
        tile[i][tx] = src[(size_t)(by + i) * DIM + (bx + tx)];
    __syncthreads();
    #pragma unroll
    for (int i = ty; i < 32; i += 8)
        dst[(size_t)(bx + i) * DIM + (by + tx)] = f2bf(tile[tx][i]);
}

// ------------- K1b: pack Wh pair-major fp16: WhP[p][j] = (W[512+2p][j], W[512+2p+1][j]) -------------
__global__ __launch_bounds__(256) void pack_wh_kernel(const float* __restrict__ W,
                                                      half2_t* __restrict__ WhP) {
    const int gid = blockIdx.x * 256 + threadIdx.x;   // p*512 + j
    const int p = gid >> 9, jj = gid & 511;
    float lo = W[(size_t)(512 + 2 * p) * DIM + jj];
    float hi = W[(size_t)(512 + 2 * p + 1) * DIM + jj];
    half2_t v; v[0] = (_Float16)lo; v[1] = (_Float16)hi;
    WhP[gid] = v;
}

// ---------------- K2: Z = X @ Wx + bias  (bf16 MFMA, fp32 A loaded direct) ----------------
__global__ __launch_bounds__(256) void gemm_z_kernel(const float* __restrict__ X,            // [32768][512] f32
                                                     const unsigned short* __restrict__ WxT, // [512 n][512 k] bf16
                                                     const float* __restrict__ bias,         // [512]
                                                     _Float16* __restrict__ Zo) {            // [32768][512] f16
    const int bm   = blockIdx.y;
    const int bn   = blockIdx.x;
    const int wave = threadIdx.x >> 6;
    const int lane = threadIdx.x & 63;
    const int mBase = bm * 128 + (wave >> 1) * 64;
    const int nBase = bn * 128 + (wave & 1) * 64;
    const int l15 = lane & 15;
    const int q   = lane >> 4;
    f32x4 acc[4][4] = {};
    for (int kt = 0; kt < 512; kt += 32) {
        const int kk = kt + q * 8;
        bf16x8 a[4], b[4];
        #pragma unroll
        for (int i = 0; i < 4; ++i) {
            const float* ap = X + (size_t)(mBase + i * 16 + l15) * DIM + kk;
            float4 f0 = *(const float4*)(ap);
            float4 f1 = *(const float4*)(ap + 4);
            bf16x8 av;
            av[0] = (short)f2bf(f0.x); av[1] = (short)f2bf(f0.y);
            av[2] = (short)f2bf(f0.z); av[3] = (short)f2bf(f0.w);
            av[4] = (short)f2bf(f1.x); av[5] = (short)f2bf(f1.y);
            av[6] = (short)f2bf(f1.z); av[7] = (short)f2bf(f1.w);
            a[i] = av;
        }
        #pragma unroll
        for (int i = 0; i < 4; ++i)
            b[i] = *(const bf16x8*)(WxT + (size_t)(nBase + i * 16 + l15) * DIM + kk);
        #pragma unroll
        for (int mi = 0; mi < 4; ++mi)
            #pragma unroll
            for (int ni = 0; ni < 4; ++ni)
                acc[mi][ni] = __builtin_amdgcn_mfma_f32_16x16x32_bf16(a[mi], b[ni], acc[mi][ni], 0, 0, 0);
    }
    #pragma unroll
    for (int ni = 0; ni < 4; ++ni) {
        const int col = nBase + ni * 16 + l15;
        const float bv = bias[col];
        #pragma unroll
        for (int mi = 0; mi < 4; ++mi) {
            #pragma unroll
            for (int rg = 0; rg < 4; ++rg) {
                const int row = mBase + mi * 16 + q * 4 + rg;
                Zo[(size_t)row * DIM + col] = (_Float16)(acc[mi][ni][rg] + bv);
            }
        }
    }
}

// ---------------- K3: sequential recurrence, 1 WG (1024 thr, 16 waves) per batch row ----------------
// Wave w, lane l: column j = w*32 + (l&31); k-half kh = l>>5 accumulates pairs [kh*128, kh*128+128).
// Combine halves with one __shfl_xor(s,32) — no extra barrier, no extra LDS traffic.
// W per thread-half: 80 pairs pinned in VGPRs, 32 in LDS (b128-packed), 16 streamed from L2/step.
// 4 waves/SIMD (vs 2 before) hides LDS/stream/barrier latency; VALU issue floor unchanged.
__global__ __launch_bounds__(1024, 4) void rnn_rec_kernel(const _Float16* __restrict__ Z,    // [T][B][512] f16
                                                          const half2_t* __restrict__ WhP,  // [256 p][512 j]
                                                          const float* __restrict__ h0,     // [512]
                                                          float* __restrict__ out) {        // [T][B][512]
    __shared__ half8_t wlds4[(LDS_PAIRS / 4) * 1024];  // [g][tid]: pairs (kh*128+80+4g..+3) of col j (128 KB)
    __shared__ _Float16 hsh[2][DIM];                   // 2 KB
    const int r   = blockIdx.x;
    const int tid = threadIdx.x;
    const int l   = tid & 63;
    const int wv  = tid >> 6;
    const int j   = (wv << 5) | (l & 31);   // column [0,512)
    const int kh  = l >> 5;                 // k-half

    const half2_t* Wcol = WhP + (size_t)(kh * 128) * DIM + j;   // pair q of this half: Wcol[q*DIM]

    // stage LDS W slice: 4 coalesced b32 global reads -> one b128 LDS write per group
    #pragma unroll
    for (int g = 0; g < LDS_PAIRS / 4; ++g) {
        half2_t p0 = Wcol[(size_t)(REG_PAIRS + 4 * g + 0) * DIM];
        half2_t p1 = Wcol[(size_t)(REG_PAIRS + 4 * g + 1) * DIM];
        half2_t p2 = Wcol[(size_t)(REG_PAIRS + 4 * g + 2) * DIM];
        half2_t p3 = Wcol[(size_t)(REG_PAIRS + 4 * g + 3) * DIM];
        half8_t v;
        v[0] = p0[0]; v[1] = p0[1]; v[2] = p1[0]; v[3] = p1[1];
        v[4] = p2[0]; v[5] = p2[1]; v[6] = p3[0]; v[7] = p3[1];
        wlds4[g * 1024 + tid] = v;
    }
    // register-resident W, pinned (opaque to the allocator -> cannot rematerialize)
    half2_t w[REG_PAIRS];
    #pragma unroll
    for (int p = 0; p < REG_PAIRS; ++p) w[p] = Wcol[(size_t)p * DIM];
    #pragma unroll
    for (int p = 0; p < REG_PAIRS; ++p) asm volatile("" : "+v"(w[p]));

    float h = h0[j];
    if (kh == 0) {
        out[(size_t)r * DIM + j] = h;
        hsh[0][j] = (_Float16)h;
    }
    __syncthreads();

    float zv = (kh == 0) ? (float)Z[(size_t)r * DIM + j] : 0.0f;

    for (int t = 0; t < T_STEPS - 1; ++t) {
        // prefetch next-step z (independent of h); only kh==0 lanes need it
        float zn = 0.0f;
        if (kh == 0) zn = (float)Z[((size_t)(t + 1) * BATCH + r) * DIM + j];
        // stream chunk 0 (pairs q=112..119) issued now, consumed at tail
        half2_t sw0[8];
        #pragma unroll
        for (int p = 0; p < 8; ++p)
            sw0[p] = Wcol[(size_t)(REG_PAIRS + LDS_PAIRS + p) * DIM];

        // this half's h window: chunks [kh*32, kh*32+32) of 8 halves each
        const half8_t* h8 = (const half8_t*)&hsh[t & 1][0] + (kh << 5);
        float a0 = zv, a1 = 0.f, a2 = 0.f, a3 = 0.f;
        #pragma unroll
        for (int c = 0; c < REG_PAIRS / 4; ++c) {          // 20 chunks, register W
            half8_t hv = h8[c];
            a0 = __builtin_amdgcn_fdot2(w[4*c+0], __builtin_shufflevector(hv, hv, 0, 1), a0, false);
            a1 = __builtin_amdgcn_fdot2(w[4*c+1], __builtin_shufflevector(hv, hv, 2, 3), a1, false);
            a2 = __builtin_amdgcn_fdot2(w[4*c+2], __builtin_shufflevector(hv, hv, 4, 5), a2, false);
            a3 = __builtin_amdgcn_fdot2(w[4*c+3], __builtin_shufflevector(hv, hv, 6, 7), a3, false);
        }
        // stream chunk 1 (pairs q=120..127)
        half2_t sw1[8];
        #pragma unroll
        for (int p = 0; p < 8; ++p)
            sw1[p] = Wcol[(size_t)(REG_PAIRS + LDS_PAIRS + 8 + p) * DIM];
        #pragma unroll
        for (int g = 0; g < LDS_PAIRS / 4; ++g) {          // 8 chunks, LDS W (b128)
            half8_t hv = h8[REG_PAIRS / 4 + g];
            half8_t wv8 = wlds4[g * 1024 + tid];
            a0 = __builtin_amdgcn_fdot2(__builtin_shufflevector(wv8, wv8, 0, 1), __builtin_shufflevector(hv, hv, 0, 1), a0, false);
            a1 = __builtin_amdgcn_fdot2(__builtin_shufflevector(wv8, wv8, 2, 3), __builtin_shufflevector(hv, hv, 2, 3), a1, false);
            a2 = __builtin_amdgcn_fdot2(__builtin_shufflevector(wv8, wv8, 4, 5), __builtin_shufflevector(hv, hv, 4, 5), a2, false);
            a3 = __builtin_amdgcn_fdot2(__builtin_shufflevector(wv8, wv8, 6, 7), __builtin_shufflevector(hv, hv, 6, 7), a3, false);
        }
        #pragma unroll
        for (int c = 0; c < 2; ++c) {                      // stream chunk 0 consume (chunks 28,29)
            half8_t hv = h8[(REG_PAIRS + LDS_PAIRS) / 4 + c];
            a0 = __builtin_amdgcn_fdot2(sw0[4*c+0], __builtin_shufflevector(hv, hv, 0, 1), a0, false);
            a1 = __builtin_amdgcn_fdot2(sw0[4*c+1], __builtin_shufflevector(hv, hv, 2, 3), a1, false);
            a2 = __builtin_amdgcn_fdot2(sw0[4*c+2], __builtin_shufflevector(hv, hv, 4, 5), a2, false);
            a3 = __builtin_amdgcn_fdot2(sw0[4*c+3], __builtin_shufflevector(hv, hv, 6, 7), a3, false);
        }
        #pragma unroll
        for (int c = 0; c < 2; ++c) {                      // stream chunk 1 consume (chunks 30,31)
            half8_t hv = h8[(REG_PAIRS + LDS_PAIRS) / 4 + 2 + c];
            a0 = __builtin_amdgcn_fdot2(sw1[4*c+0], __builtin_shufflevector(hv, hv, 0, 1), a0, false);
            a1 = __builtin_amdgcn_fdot2(sw1[4*c+1], __builtin_shufflevector(hv, hv, 2, 3), a1, false);
            a2 = __builtin_amdgcn_fdot2(sw1[4*c+2], __builtin_shufflevector(hv, hv, 4, 5), a2, false);
            a3 = __builtin_amdgcn_fdot2(sw1[4*c+3], __builtin_shufflevector(hv, hv, 6, 7), a3, false);
        }
        float s = (a0 + a1) + (a2 + a3);
        s += __shfl_xor(s, 32, 64);                        // combine k-halves (one ds_bpermute)
        float hn = fast_tanh(s);
        if (kh == 0) {
            out[((size_t)(t + 1) * BATCH + r) * DIM + j] = hn;
            hsh[(t + 1) & 1][j] = (_Float16)hn;
        }
        zv = zn;
        // LDS-only drain + barrier: out-stores / z-prefetch / W-stream stay in flight
        asm volatile("s_waitcnt lgkmcnt(0)\n\ts_barrier" ::: "memory");
    }
}

extern "C" void kernel_launch(void* const* d_in, const int* in_sizes, int n_in,
                              void* d_out, int out_size, void* d_ws, size_t ws_size,
                              hipStream_t stream) {
    const float* X    = (const float*)d_in[0];   // [512][64][512]
    const float* W    = (const float*)d_in[1];   // [1024][512]
    const float* bias = (const float*)d_in[2];   // [512]
    const float* h0   = (const float*)d_in[3];   // [512]
    float* out = (float*)d_out;

    char* ws = (char*)d_ws;
    unsigned short* WxT = (unsigned short*)(ws);                 //    524,288 B
    half2_t*        WhP = (half2_t*)(ws + 524288);               //    524,288 B
    _Float16*       Zh  = (_Float16*)(ws + 1048576);             // 33,554,432 B
                                                                  // total 34,603,008 B

    dim3 tb(32, 8);
    tr_cvt_kernel<<<dim3(16, 16), tb, 0, stream>>>(W, WxT);            // Wx^T bf16
    pack_wh_kernel<<<512, 256, 0, stream>>>(W, WhP);                   // Wh pair-major fp16
    gemm_z_kernel<<<dim3(4, 256), 256, 0, stream>>>(X, WxT, bias, Zh);
    rnn_rec_kernel<<<64, 1024, 0, stream>>>(Zh, WhP, h0, out);
}